// Round 13
// baseline (934.034 us; speedup 1.0000x reference)
//
#include <hip/hip_runtime.h>
#include <hip/hip_bf16.h>

// ---------------------------------------------------------------------------
// VQ-VAE forward, fp32. NCHW.
// R28 = R27 resubmitted verbatim (R27 bench failed on container acquisition;
// diff audited: staging covers exactly 2048 f4 with 4x512 threads, halo
// zeroing covers exactly 128 rows, all LDS/global accesses aligned+in-bounds,
// same 5-barrier skeleton as validated R19 structure).
// R27: grid-supply fix. R26 post-mortem: shrinking LDS to 51KB raised the
// residency CEILING to 3 blocks/CU but grid=512 supplies only 2 blocks/CU
// of WORK -- occupancy stayed 38%. e2's edge was its grid of 1024, not its
// tile size. Fix: px-split conv3_tile and res_tile to 128 px/block (2 out
// rows): grid 1024, tile [32ci][4r][68] = 34KB -> 4 blocks/CU resident AND
// available. Threads: 64 px-pair lanes x 8 cout-groups; same aligned L/M/R
// b64 reads (2-way free). convt_tile held back as A/B control.
// Pure output->thread reassignment: staged values + per-output FMA chains
// bit-identical => VQ argmin safe (R3). Others byte-identical to R26.
// ---------------------------------------------------------------------------

__device__ __forceinline__ float rp_elem(const float* __restrict__ src,
                                         int i, int COUT, int CIN, int KK)
{
    const int co = i % COUT;
    const int t  = i / COUT;
    const int kk = t % KK;
    const int ci = t / KK;
    return src[(co * CIN + ci) * KK + kk];
}

// One kernel repacks all weights + codebook-transpose into WR.
__global__ __launch_bounds__(256) void repack_all(
    const float* __restrict__ e1,  const float* __restrict__ e2,
    const float* __restrict__ er1a, const float* __restrict__ er1b,
    const float* __restrict__ er2a, const float* __restrict__ er2b,
    const float* __restrict__ pre, const float* __restrict__ d1,
    const float* __restrict__ dr1a, const float* __restrict__ dr1b,
    const float* __restrict__ dr2a, const float* __restrict__ dr2b,
    const float* __restrict__ t1, const float* __restrict__ cb,
    float* __restrict__ WR)
{
    const int idx = blockIdx.x * 256 + threadIdx.x;
    if (idx >= 221696) return;
    float v;
    if      (idx < 512)    v = rp_elem(e1,   idx,          32,  1, 16);
    else if (idx < 33280)  v = rp_elem(e2,   idx - 512,    64, 32, 16);
    else if (idx < 51712)  v = rp_elem(er1a, idx - 33280,  32, 64,  9);
    else if (idx < 53760)  v = rp_elem(er1b, idx - 51712,  64, 32,  1);
    else if (idx < 72192)  v = rp_elem(er2a, idx - 53760,  32, 64,  9);
    else if (idx < 74240)  v = rp_elem(er2b, idx - 72192,  64, 32,  1);
    else if (idx < 78336)  v = rp_elem(pre,  idx - 74240,  64, 64,  1);
    else if (idx < 115200) v = rp_elem(d1,   idx - 78336,  64, 64,  9);
    else if (idx < 133632) v = rp_elem(dr1a, idx - 115200, 32, 64,  9);
    else if (idx < 135680) v = rp_elem(dr1b, idx - 133632, 64, 32,  1);
    else if (idx < 154112) v = rp_elem(dr2a, idx - 135680, 32, 64,  9);
    else if (idx < 156160) v = rp_elem(dr2b, idx - 154112, 64, 32,  1);
    else if (idx < 188928) {
        // t1: [pr][k2=ci*2+ta][q=pc*2+tb][co]
        const int i  = idx - 156160;
        const int co = i & 31;
        const int q  = (i >> 5) & 3;
        const int k2 = (i >> 7) & 127;
        const int pr = i >> 14;
        const int pc = q >> 1, tb = q & 1;
        const int ci = k2 >> 1, ta = k2 & 1;
        const int kh = (1 - pr) + 2 * ta, kw = (1 - pc) + 2 * tb;
        v = t1[((ci * 32 + co) * 4 + kh) * 4 + kw];
    } else {
        const int i = idx - 188928;           // cbT: [dim][code]
        const int code = i & 511;
        const int dim  = i >> 9;
        v = cb[code * 64 + dim];
    }
    WR[idx] = v;
}

// ee[k] = sum_i cb[k][i]^2, exact ascending fmaf chain (matches reference).
__global__ __launch_bounds__(256) void vq_prep_ee(
    const float* __restrict__ cb, float* __restrict__ ee)
{
    const int k = blockIdx.x * 256 + threadIdx.x;  // grid(2) -> k < 512
    const float* __restrict__ cp = cb + (size_t)k * 64;
    float s = 0.0f;
#pragma unroll
    for (int i = 0; i < 64; i++) s = fmaf(cp[i], cp[i], s);
    ee[k] = s;
}

// GEMM-form conv (validated R13) — still used by e1.
template<int CTOT, int CPB, int CIN, int K, int S, int PAD,
         bool RELU_IN, bool HAS_BIAS, bool RESID, bool RELU_OUT>
__global__ __launch_bounds__(256) void conv_gemm(
    const float* __restrict__ in, const float* __restrict__ wr,
    const float* __restrict__ bias, const float* __restrict__ resid,
    float* __restrict__ out,
    int H, int W, int OH, int OW)
{
    constexpr int KK  = K * K;
    constexpr int CIC = (K == 1) ? 8 : 1;
    constexpr int TS  = (K == 4) ? 2 : 1;
    constexpr int KC  = CIC * KK / TS;
    constexpr int NCH = (CIN * TS) / CIC;
    constexpr int NT  = 256;
    constexpr int CPTHD = CPB / 4;
    __shared__ __align__(16) float As[2][KC * NT];

    const int tid = threadIdx.x;
    const int tpx = tid & 63;
    const int tco = __builtin_amdgcn_readfirstlane(tid >> 6);
    const int co0 = blockIdx.y * CPB + tco * CPTHD;

    const int ohow = OH * OW;
    const int n_st = blockIdx.x * NT + tid;
    const int b_st = n_st / ohow;
    const int hw_s = n_st % ohow;
    const int ih0 = (hw_s / OW) * S - PAD;
    const int iw0 = (hw_s % OW) * S - PAD;
    const float* __restrict__ inb = in + (size_t)b_st * CIN * H * W;

    float acc[CPTHD][4];
#pragma unroll
    for (int c = 0; c < CPTHD; c++) {
        const float bz = HAS_BIAS ? bias[co0 + c] : 0.0f;
#pragma unroll
        for (int q = 0; q < 4; q++) acc[c][q] = bz;
    }

    float pf[KC];
    auto stage_load = [&](int ch) {
#pragma unroll
        for (int t = 0; t < KC; t++) {
            int ci, kh, kw;
            if constexpr (K == 1) {
                ci = ch * 8 + t; kh = 0; kw = 0;
            } else if constexpr (K == 3) {
                ci = ch; kh = t / 3; kw = t % 3;
            } else {                                 // K == 4, TS = 2
                ci = ch >> 1;
                const int kk = ((ch & 1) << 3) + t;
                kh = kk >> 2; kw = kk & 3;
            }
            const int ih = ih0 + kh, iw = iw0 + kw;
            float v = 0.0f;
            if (ih >= 0 && ih < H && iw >= 0 && iw < W)
                v = inb[(size_t)ci * H * W + ih * W + iw];
            if (RELU_IN) v = fmaxf(v, 0.0f);
            pf[t] = v;
        }
    };

    stage_load(0);
#pragma unroll
    for (int t = 0; t < KC; t++) As[0][t * NT + tid] = pf[t];
    __syncthreads();

#pragma unroll 2
    for (int c = 0; c < NCH; c++) {
        const int cur = c & 1;
        if (c + 1 < NCH) stage_load(c + 1);

#pragma unroll
        for (int t = 0; t < KC; t++) {
            const float4 a4 = *(const float4*)(As[cur] + t * NT + tpx * 4);
            const float* __restrict__ wk =
                wr + (size_t)(c * KC + t) * CTOT + co0;
#pragma unroll
            for (int cc = 0; cc < CPTHD; cc++) {
                const float w = wk[cc];
                acc[cc][0] = fmaf(a4.x, w, acc[cc][0]);
                acc[cc][1] = fmaf(a4.y, w, acc[cc][1]);
                acc[cc][2] = fmaf(a4.z, w, acc[cc][2]);
                acc[cc][3] = fmaf(a4.w, w, acc[cc][3]);
            }
        }

        if (c + 1 < NCH) {
#pragma unroll
            for (int t = 0; t < KC; t++) As[1 - cur][t * NT + tid] = pf[t];
        }
        __syncthreads();
    }

    const int n_c  = blockIdx.x * NT + tpx * 4;
    const int b_c  = n_c / ohow;
    const int hw_c = n_c % ohow;
    float* __restrict__ op = out + (size_t)b_c * CTOT * ohow + hw_c;
    const float* __restrict__ rp =
        RESID ? (resid + (size_t)b_c * CTOT * ohow + hw_c) : nullptr;
#pragma unroll
    for (int c = 0; c < CPTHD; c++) {
        const size_t off = (size_t)(co0 + c) * ohow;
        float4 r = make_float4(acc[c][0], acc[c][1], acc[c][2], acc[c][3]);
        if (RESID) {
            const float4 rv = *(const float4*)(rp + off);
            r.x += rv.x; r.y += rv.y; r.z += rv.z; r.w += rv.w;
        }
        if (RELU_OUT) {
            r.x = fmaxf(r.x, 0.f); r.y = fmaxf(r.y, 0.f);
            r.z = fmaxf(r.z, 0.f); r.w = fmaxf(r.w, 0.f);
        }
        *(float4*)(op + off) = r;
    }
}

// Fused residual block, R27: 128 px/block (2 out rows), grid 1024.
// tile [32ci][4r][68] = 34KB -> 4 blocks/CU. conv1: 4co x 2px/thread
// (8 cout-groups); conv2: 8co x 2px. Chains bit-identical to R19-R26.
__global__ __launch_bounds__(512, 4) void res_tile(
    const float* __restrict__ in, const float* __restrict__ wr1,
    const float* __restrict__ wr2, float* __restrict__ out)
{
    // tile: [ci<32][r4<4][68] = 8704 floats (34KB); mid[32][128] overlays.
    __shared__ __align__(16) float S[8704];

    const int tid = threadIdx.x;
    const int pp  = tid & 63;                                   // px-pair
    const int cog = __builtin_amdgcn_readfirstlane(tid >> 6);   // 0..7
    const int a   = pp >> 5;               // out row in block (0..1)
    const int c0  = (pp & 31) * 2;         // out col base (0,2,..,62)

    const int n0   = blockIdx.x * 128;
    const int b    = n0 >> 12;
    const int row0 = (n0 & 4095) >> 6;     // 2 rows of 64 (even)
    const float* __restrict__ inb = in + (size_t)b * 64 * 4096;

    // zero halo cols {0,1,66,67} of the 128 tile rows (written once).
    if (tid < 128) {
        float* __restrict__ rp0 = S + tid * 68;
        *(float2*)(rp0)      = make_float2(0.f, 0.f);
        *(float2*)(rp0 + 66) = make_float2(0.f, 0.f);
    }

    float4 pf4[4];
    auto stage_issue = [&](int half) {
#pragma unroll
        for (int m = 0; m < 4; m++) {
            const int f4 = m * 512 + tid;        // 0..2047
            const int ci  = f4 >> 6;
            const int rem = f4 & 63;
            const int r4  = rem >> 4;            // 0..3
            const int s   = rem & 15;            // iw = 4s..4s+3
            const int ih  = row0 + r4 - 1;
            float4 v = make_float4(0.f, 0.f, 0.f, 0.f);
            if (ih >= 0 && ih < 64)
                v = *(const float4*)(inb + (size_t)(half * 32 + ci) * 4096
                                     + ih * 64 + s * 4);
            pf4[m] = v;
        }
    };
    auto stage_commit = [&]() {
#pragma unroll
        for (int m = 0; m < 4; m++) {
            const int f4 = m * 512 + tid;
            const int ci  = f4 >> 6;
            const int rem = f4 & 63;
            const int r4  = rem >> 4;
            const int s   = rem & 15;
            float4 v = pf4[m];
            v.x = fmaxf(v.x, 0.f); v.y = fmaxf(v.y, 0.f);
            v.z = fmaxf(v.z, 0.f); v.w = fmaxf(v.w, 0.f);
            float* __restrict__ rowp = S + (ci * 4 + r4) * 68 + s * 4;
            *(float2*)(rowp + 2) = make_float2(v.x, v.y);
            *(float2*)(rowp + 4) = make_float2(v.z, v.w);
        }
    };

    const int co1 = cog * 4;
    float acc1[4][2];
#pragma unroll
    for (int c = 0; c < 4; c++) { acc1[c][0] = 0.0f; acc1[c][1] = 0.0f; }

    auto conv1_half = [&](int h) {
#pragma unroll 2
        for (int c = 0; c < 32; c++) {
            const float* __restrict__ wb =
                wr1 + (size_t)((h * 32 + c) * 9) * 32 + co1;
#pragma unroll
            for (int kh = 0; kh < 3; kh++) {
                const float* __restrict__ tp =
                    S + c * 272 + (a + kh) * 68 + 2 + c0;
                const float2 L = *(const float2*)(tp - 2);
                const float2 M = *(const float2*)(tp);
                const float2 R = *(const float2*)(tp + 2);
                const float xm = L.y;
                const float x0 = M.x;
                const float x1 = M.y;
                const float x2 = R.x;
                const float* __restrict__ wk = wb + (size_t)(kh * 3) * 32;
#pragma unroll
                for (int cc = 0; cc < 4; cc++) {     // kw = 0
                    const float w = wk[cc];
                    acc1[cc][0] = fmaf(xm, w, acc1[cc][0]);
                    acc1[cc][1] = fmaf(x0, w, acc1[cc][1]);
                }
#pragma unroll
                for (int cc = 0; cc < 4; cc++) {     // kw = 1
                    const float w = wk[32 + cc];
                    acc1[cc][0] = fmaf(x0, w, acc1[cc][0]);
                    acc1[cc][1] = fmaf(x1, w, acc1[cc][1]);
                }
#pragma unroll
                for (int cc = 0; cc < 4; cc++) {     // kw = 2
                    const float w = wk[64 + cc];
                    acc1[cc][0] = fmaf(x1, w, acc1[cc][0]);
                    acc1[cc][1] = fmaf(x2, w, acc1[cc][1]);
                }
            }
        }
    };

    stage_issue(0);
    stage_commit();
    __syncthreads();
    stage_issue(1);
    conv1_half(0);
    __syncthreads();
    stage_commit();
    __syncthreads();
    conv1_half(1);
    __syncthreads();

    // mid[co][px] (32x128 = 4096 floats) overlays tile region.
#pragma unroll
    for (int cc = 0; cc < 4; cc++)
        *(float2*)(S + (co1 + cc) * 128 + pp * 2) =
            make_float2(acc1[cc][0], acc1[cc][1]);
    __syncthreads();

    const int co2 = cog * 8;
    float acc2[8][2];
#pragma unroll
    for (int c = 0; c < 8; c++) { acc2[c][0] = 0.0f; acc2[c][1] = 0.0f; }

#pragma unroll 4
    for (int k = 0; k < 32; k++) {
        float2 m2 = *(const float2*)(S + k * 128 + pp * 2);
        m2.x = fmaxf(m2.x, 0.f);
        m2.y = fmaxf(m2.y, 0.f);
        const float* __restrict__ wk = wr2 + (size_t)k * 64 + co2;
#pragma unroll
        for (int cc = 0; cc < 8; cc++) {
            const float w = wk[cc];
            acc2[cc][0] = fmaf(m2.x, w, acc2[cc][0]);
            acc2[cc][1] = fmaf(m2.y, w, acc2[cc][1]);
        }
    }

    const int hw = (n0 & 4095) + a * 64 + c0;
    const float* __restrict__ rp = inb + hw;
    float* __restrict__ op = out + (size_t)b * 64 * 4096 + hw;
#pragma unroll
    for (int cc = 0; cc < 8; cc++) {
        const size_t off = (size_t)(co2 + cc) * 4096;
        const float2 rv = *(const float2*)(rp + off);
        *(float2*)(op + off) =
            make_float2(acc2[cc][0] + rv.x, acc2[cc][1] + rv.y);
    }
}

// R27: stage-once 3x3 conv 64ci->64co (d1), 128 px/block, grid 1024.
// tile [32ci][4r][68] = 34KB -> 4 blocks/CU. 8co x 2px/thread.
__global__ __launch_bounds__(512, 4) void conv3_tile(
    const float* __restrict__ in, const float* __restrict__ wr,
    const float* __restrict__ bias, float* __restrict__ out)
{
    __shared__ __align__(16) float S[8704];    // [ci<32][4][68], 34KB

    const int tid = threadIdx.x;
    const int pp  = tid & 63;
    const int cog = __builtin_amdgcn_readfirstlane(tid >> 6);   // 0..7
    const int a   = pp >> 5;
    const int c0  = (pp & 31) * 2;

    const int n0   = blockIdx.x * 128;
    const int b    = n0 >> 12;
    const int row0 = (n0 & 4095) >> 6;
    const float* __restrict__ inb = in + (size_t)b * 64 * 4096;

    if (tid < 128) {
        float* __restrict__ rp0 = S + tid * 68;
        *(float2*)(rp0)      = make_float2(0.f, 0.f);
        *(float2*)(rp0 + 66) = make_float2(0.f, 0.f);
    }

    float4 pf4[4];
    auto stage_issue = [&](int half) {
#pragma unroll
        for (int m = 0; m < 4; m++) {
            const int f4 = m * 512 + tid;
            const int ci  = f4 >> 6;
            const int rem = f4 & 63;
            const int r4  = rem >> 4;
            const int s   = rem & 15;
            const int ih  = row0 + r4 - 1;
            float4 v = make_float4(0.f, 0.f, 0.f, 0.f);
            if (ih >= 0 && ih < 64)
                v = *(const float4*)(inb + (size_t)(half * 32 + ci) * 4096
                                     + ih * 64 + s * 4);
            pf4[m] = v;
        }
    };
    auto stage_commit = [&]() {
#pragma unroll
        for (int m = 0; m < 4; m++) {
            const int f4 = m * 512 + tid;
            const int ci  = f4 >> 6;
            const int rem = f4 & 63;
            const int r4  = rem >> 4;
            const int s   = rem & 15;
            const float4 v = pf4[m];
            float* __restrict__ rowp = S + (ci * 4 + r4) * 68 + s * 4;
            *(float2*)(rowp + 2) = make_float2(v.x, v.y);   // no relu
            *(float2*)(rowp + 4) = make_float2(v.z, v.w);
        }
    };

    const int co1 = cog * 8;
    float acc[8][2];
#pragma unroll
    for (int cc = 0; cc < 8; cc++) {
        const float bz = bias[co1 + cc];
        acc[cc][0] = bz; acc[cc][1] = bz;
    }

    auto conv_half = [&](int h) {
#pragma unroll 2
        for (int c = 0; c < 32; c++) {
            const float* __restrict__ wb =
                wr + (size_t)((h * 32 + c) * 9) * 64 + co1;
#pragma unroll
            for (int kh = 0; kh < 3; kh++) {
                const float* __restrict__ tp =
                    S + c * 272 + (a + kh) * 68 + 2 + c0;
                const float2 L = *(const float2*)(tp - 2);
                const float2 M = *(const float2*)(tp);
                const float2 R = *(const float2*)(tp + 2);
                const float xm = L.y;
                const float x0 = M.x;
                const float x1 = M.y;
                const float x2 = R.x;
                const float* __restrict__ wk = wb + (size_t)(kh * 3) * 64;
#pragma unroll
                for (int cc = 0; cc < 8; cc++) {     // kw = 0
                    const float w = wk[cc];
                    acc[cc][0] = fmaf(xm, w, acc[cc][0]);
                    acc[cc][1] = fmaf(x0, w, acc[cc][1]);
                }
#pragma unroll
                for (int cc = 0; cc < 8; cc++) {     // kw = 1
                    const float w = wk[64 + cc];
                    acc[cc][0] = fmaf(x0, w, acc[cc][0]);
                    acc[cc][1] = fmaf(x1, w, acc[cc][1]);
                }
#pragma unroll
                for (int cc = 0; cc < 8; cc++) {     // kw = 2
                    const float w = wk[128 + cc];
                    acc[cc][0] = fmaf(x1, w, acc[cc][0]);
                    acc[cc][1] = fmaf(x2, w, acc[cc][1]);
                }
            }
        }
    };

    stage_issue(0);
    stage_commit();
    __syncthreads();
    stage_issue(1);
    conv_half(0);
    __syncthreads();
    stage_commit();
    __syncthreads();
    conv_half(1);

    const int hw = (n0 & 4095) + a * 64 + c0;
    float* __restrict__ op = out + (size_t)b * 64 * 4096 + hw;
#pragma unroll
    for (int cc = 0; cc < 8; cc++)
        *(float2*)(op + (size_t)(co1 + cc) * 4096) =
            make_float2(acc[cc][0], acc[cc][1]);
}

// R25: stage-once stride-2 4x4 conv 32ci->64co (e2), deinterleaved LDS.
// (validated R25 — e2 dropped out of top-5)
__global__ __launch_bounds__(512, 4) void conv4s2_tile(
    const float* __restrict__ in, const float* __restrict__ wr,
    const float* __restrict__ bias, float* __restrict__ out)
{
    // [ci<16][r6<6][E 68 | O 68] = 13056 floats, 51KB
    __shared__ __align__(16) float S[13056];

    const int tid = threadIdx.x;
    const int p   = tid & 127;                                  // out px
    const int cog = __builtin_amdgcn_readfirstlane(tid >> 7);   // 0..3
    const int a   = p >> 6;                 // out row (0..1)
    const int j   = p & 63;                 // out col

    const int n0   = blockIdx.x * 128;
    const int b    = n0 >> 12;
    const int row0 = (n0 & 4095) >> 6;      // 2 out rows of 64
    const float* __restrict__ inb = in + (size_t)b * 32 * 16384;

    float4 pf4[7];
    auto stage_issue = [&](int half) {
#pragma unroll
        for (int m = 0; m < 7; m++) {
            const int f4 = m * 512 + tid;
            float4 v = make_float4(0.f, 0.f, 0.f, 0.f);
            if (f4 < 3264) {
                const int ci  = f4 / 204;
                const int rem = f4 - ci * 204;
                const int r6  = rem / 34;
                const int s   = rem - r6 * 34;
                const int ih  = 2 * row0 - 1 + r6;
                if (ih >= 0 && ih < 128 && s >= 1 && s <= 32)
                    v = *(const float4*)(inb + (size_t)(half * 16 + ci) * 16384
                                         + ih * 128 + (s - 1) * 4);
            }
            pf4[m] = v;
        }
    };
    auto stage_commit = [&]() {
#pragma unroll
        for (int m = 0; m < 7; m++) {
            const int f4 = m * 512 + tid;
            if (f4 < 3264) {
                const int ci  = f4 / 204;
                const int rem = f4 - ci * 204;
                const int r6  = rem / 34;
                const int s   = rem - r6 * 34;
                const float4 v = pf4[m];
                float* __restrict__ rowp = S + (ci * 6 + r6) * 136;
                *(float2*)(rowp + 2 * s)      = make_float2(v.x, v.z);  // E
                *(float2*)(rowp + 68 + 2 * s) = make_float2(v.y, v.w);  // O
            }
        }
    };

    const int co1 = cog * 16;
    float acc[16];
#pragma unroll
    for (int cc = 0; cc < 16; cc++) acc[cc] = bias[co1 + cc];

    auto conv_half = [&](int h) {
#pragma unroll 2
        for (int c = 0; c < 16; c++) {
            const float* __restrict__ wb =
                wr + (size_t)((h * 16 + c) * 16) * 64 + co1;
#pragma unroll
            for (int kh = 0; kh < 4; kh++) {
                const float* __restrict__ rowp =
                    S + (c * 6 + 2 * a + kh) * 136;
                const float e0 = rowp[j + 2];        // iw = 2j
                const float e1 = rowp[j + 3];        // iw = 2j+2
                const float o0 = rowp[68 + j + 1];   // iw = 2j-1
                const float o1 = rowp[68 + j + 2];   // iw = 2j+1
                const float* __restrict__ wk = wb + (size_t)(kh * 4) * 64;
#pragma unroll
                for (int cc = 0; cc < 16; cc++)      // kw = 0 (iw 2j-1)
                    acc[cc] = fmaf(o0, wk[cc], acc[cc]);
#pragma unroll
                for (int cc = 0; cc < 16; cc++)      // kw = 1 (iw 2j)
                    acc[cc] = fmaf(e0, wk[64 + cc], acc[cc]);
#pragma unroll
                for (int cc = 0; cc < 16; cc++)      // kw = 2 (iw 2j+1)
                    acc[cc] = fmaf(o1, wk[128 + cc], acc[cc]);
#pragma unroll
                for (int cc = 0; cc < 16; cc++)      // kw = 3 (iw 2j+2)
                    acc[cc] = fmaf(e1, wk[192 + cc], acc[cc]);
            }
        }
    };

    stage_issue(0);
    stage_commit();
    __syncthreads();
    stage_issue(1);
    conv_half(0);
    __syncthreads();
    stage_commit();
    __syncthreads();
    conv_half(1);

    const int hw = (n0 & 4095) + a * 64 + j;
    float* __restrict__ op = out + (size_t)b * 64 * 4096 + hw;
#pragma unroll
    for (int cc = 0; cc < 16; cc++)
        op[(size_t)(co1 + cc) * 4096] = acc[cc];
}

// R22: stage-once 1x1 conv 64ci->64co (pre). (validated)
__global__ __launch_bounds__(512, 4) void conv1x1_tile(
    const float* __restrict__ in, const float* __restrict__ wr,
    const float* __restrict__ bias, float* __restrict__ out)
{
    __shared__ __align__(16) float S[8192];    // [ci<32][256px], 32KB

    const int tid = threadIdx.x;
    const int p   = tid & 127;                                  // px-pair
    const int cog = __builtin_amdgcn_readfirstlane(tid >> 7);   // 0..3

    const int n0  = blockIdx.x * 256;
    const int b   = n0 >> 12;
    const int hw0 = n0 & 4095;
    const float* __restrict__ inb = in + (size_t)b * 64 * 4096 + hw0;

    float4 pf4[4];
    auto stage_issue = [&](int half) {
#pragma unroll
        for (int m = 0; m < 4; m++) {
            const int f4 = m * 512 + tid;        // 0..2047
            const int ci = f4 >> 6;
            const int c4 = f4 & 63;
            pf4[m] = *(const float4*)(inb + (size_t)(half * 32 + ci) * 4096
                                      + c4 * 4);
        }
    };
    auto stage_commit = [&]() {
#pragma unroll
        for (int m = 0; m < 4; m++) {
            const int f4 = m * 512 + tid;
            *(float4*)(S + f4 * 4) = pf4[m];
        }
    };

    const int co1 = cog * 16;
    float acc[16][2];
#pragma unroll
    for (int cc = 0; cc < 16; cc++) {
        const float bz = bias[co1 + cc];
        acc[cc][0] = bz; acc[cc][1] = bz;
    }

    auto conv_half = [&](int h) {
#pragma unroll 4
        for (int c = 0; c < 32; c++) {
            const float2 x = *(const float2*)(S + c * 256 + p * 2);
            const float* __restrict__ wk =
                wr + (size_t)(h * 32 + c) * 64 + co1;
#pragma unroll
            for (int cc = 0; cc < 16; cc++) {
                const float w = wk[cc];
                acc[cc][0] = fmaf(x.x, w, acc[cc][0]);
                acc[cc][1] = fmaf(x.y, w, acc[cc][1]);
            }
        }
    };

    stage_issue(0);
    stage_commit();
    __syncthreads();
    stage_issue(1);
    conv_half(0);
    __syncthreads();
    stage_commit();
    __syncthreads();
    conv_half(1);

    float* __restrict__ op = out + (size_t)b * 64 * 4096 + hw0 + p * 2;
#pragma unroll
    for (int cc = 0; cc < 16; cc++)
        *(float2*)(op + (size_t)(co1 + cc) * 4096) =
            make_float2(acc[cc][0], acc[cc][1]);
}

// R26: stage-once transposed conv t1, 68-col tile (51KB). (unchanged)
__global__ __launch_bounds__(512, 4) void convt_tile(
    const float* __restrict__ in, const float* __restrict__ wr,
    const float* __restrict__ bias, float* __restrict__ out)
{
    __shared__ __align__(16) float S[13056];   // [ci<32][6][68], 51KB

    const int tid = threadIdx.x;
    const int p   = tid & 127;                                  // px-pair
    const int cog = __builtin_amdgcn_readfirstlane(tid >> 7);   // 0..3
    const int a   = p >> 5;                 // input row in block (0..3)
    const int c0  = (p & 31) * 2;           // input col base (0,2,..,62)

    const int n0   = blockIdx.x * 256;      // 256 input px = 4 rows
    const int b    = n0 >> 12;
    const int row0 = (n0 & 4095) >> 6;
    const float* __restrict__ inb = in + (size_t)b * 64 * 4096;

    if (tid < 192) {
        float* __restrict__ rp0 = S + tid * 68;
        *(float2*)(rp0)      = make_float2(0.f, 0.f);
        *(float2*)(rp0 + 66) = make_float2(0.f, 0.f);
    }

    float4 pf4[6];
    auto stage_issue = [&](int half) {
#pragma unroll
        for (int m = 0; m < 6; m++) {
            const int f4 = m * 512 + tid;
            const int ci  = f4 / 96;
            const int rem = f4 - ci * 96;
            const int r6  = rem >> 4;
            const int s   = rem & 15;
            const int ih  = row0 + r6 - 1;
            float4 v = make_float4(0.f, 0.f, 0.f, 0.f);
            if (ih >= 0 && ih < 64)
                v = *(const float4*)(inb + (size_t)(half * 32 + ci) * 4096
                                     + ih * 64 + s * 4);
            pf4[m] = v;
        }
    };
    auto stage_commit = [&]() {
#pragma unroll
        for (int m = 0; m < 6; m++) {
            const int f4 = m * 512 + tid;
            const int ci  = f4 / 96;
            const int rem = f4 - ci * 96;
            const int r6  = rem >> 4;
            const int s   = rem & 15;
            const float4 v = pf4[m];
            float* __restrict__ rowp = S + (ci * 6 + r6) * 68 + s * 4;
            *(float2*)(rowp + 2) = make_float2(v.x, v.y);   // no relu
            *(float2*)(rowp + 4) = make_float2(v.z, v.w);
        }
    };

    const int co1 = cog * 8;
    // acc[co][px][pc][pr]
    float acc[8][2][2][2];
#pragma unroll
    for (int cc = 0; cc < 8; cc++) {
        const float bz = bias[co1 + cc];
#pragma unroll
        for (int px = 0; px < 2; px++)
#pragma unroll
            for (int pc = 0; pc < 2; pc++) {
                acc[cc][px][pc][0] = bz;
                acc[cc][px][pc][1] = bz;
            }
    }

    auto conv_half = [&](int h) {
#pragma unroll 2
        for (int c = 0; c < 32; c++) {
            const int ci = h * 32 + c;
            float X[3][4];
#pragma unroll
            for (int r = 0; r < 3; r++) {
                const float* __restrict__ tp =
                    S + c * 408 + (a + r) * 68 + 2 + c0;
                const float2 L = *(const float2*)(tp - 2);
                const float2 M = *(const float2*)(tp);
                const float2 R = *(const float2*)(tp + 2);
                X[r][0] = L.y; X[r][1] = M.x; X[r][2] = M.y; X[r][3] = R.x;
            }
            const float* __restrict__ wb = wr + (size_t)(ci * 2) * 128 + co1;
#pragma unroll
            for (int ta = 0; ta < 2; ta++) {
                const float* X0 = X[1 - ta];
                const float* X1 = X[2 - ta];
                const float* __restrict__ wt = wb + ta * 128;
#pragma unroll
                for (int tb = 0; tb < 2; tb++) {
#pragma unroll
                    for (int pc = 0; pc < 2; pc++) {
                        const int m = pc - tb + 1;   // 0..2
                        const float* __restrict__ w0 = wt + (pc * 2 + tb) * 32;
                        const float* __restrict__ w1 = w0 + 16384;
#pragma unroll
                        for (int cc = 0; cc < 8; cc++) {
                            const float wv0 = w0[cc];
                            const float wv1 = w1[cc];
                            acc[cc][0][pc][0] =
                                fmaf(X0[m],     wv0, acc[cc][0][pc][0]);
                            acc[cc][1][pc][0] =
                                fmaf(X0[m + 1], wv0, acc[cc][1][pc][0]);
                            acc[cc][0][pc][1] =
                                fmaf(X1[m],     wv1, acc[cc][0][pc][1]);
                            acc[cc][1][pc][1] =
                                fmaf(X1[m + 1], wv1, acc[cc][1][pc][1]);
                        }
                    }
                }
            }
        }
    };

    stage_issue(0);
    stage_commit();
    __syncthreads();
    stage_issue(1);
    conv_half(0);
    __syncthreads();
    stage_commit();
    __syncthreads();
    conv_half(1);

    const int i = row0 + a;
    float* __restrict__ ob =
        out + (size_t)b * 32 * 16384 + (size_t)(2 * i) * 128 + 2 * c0;
#pragma unroll
    for (int cc = 0; cc < 8; cc++) {
        float* __restrict__ o = ob + (size_t)(co1 + cc) * 16384;
#pragma unroll
        for (int pr = 0; pr < 2; pr++) {
            const float4 v = make_float4(
                fmaxf(acc[cc][0][0][pr], 0.f), fmaxf(acc[cc][0][1][pr], 0.f),
                fmaxf(acc[cc][1][0][pr], 0.f), fmaxf(acc[cc][1][1][pr], 0.f));
            *(float4*)(o + (size_t)pr * 128) = v;
        }
    }
}

// Final transposed conv (32 -> 1). (validated)
__global__ __launch_bounds__(256) void convt2_quad(
    const float* __restrict__ in, const float* __restrict__ w,
    const float* __restrict__ bias, float* __restrict__ out, int B)
{
    const int IH = 128, IW = 128, CIN = 32, OW = 256;
    const int j = threadIdx.x & 127;
    const int i = (blockIdx.x << 1) + (threadIdx.x >> 7);
    const int b = blockIdx.y;

    const float* __restrict__ inb = in + (size_t)b * CIN * IH * IW;
    const float bz = bias[0];
    float a00 = bz, a01 = bz, a10 = bz, a11 = bz;

    const bool okm = (i > 0);
    const bool okp = (i < IH - 1);
    const bool olm = (j > 0);
    const bool olp = (j < IW - 1);

#pragma unroll 4
    for (int ci = 0; ci < CIN; ci++) {
        const float* __restrict__ p = inb + ((size_t)ci * IH + i) * IW + j;
        const float* __restrict__ wp = w + ci * 16;
        const float vmm = (okm && olm) ? p[-IW - 1] : 0.f;
        const float vm0 = okm ? p[-IW] : 0.f;
        const float vmp = (okm && olp) ? p[-IW + 1] : 0.f;
        const float v0m = olm ? p[-1] : 0.f;
        const float v00 = p[0];
        const float v0p = olp ? p[1] : 0.f;
        const float vpm = (okp && olm) ? p[IW - 1] : 0.f;
        const float vp0 = okp ? p[IW] : 0.f;
        const float vpp = (okp && olp) ? p[IW + 1] : 0.f;
        a00 = fmaf(v00, wp[1 * 4 + 1], a00);
        a00 = fmaf(v0m, wp[1 * 4 + 3], a00);
        a00 = fmaf(vm0, wp[3 * 4 + 1], a00);
        a00 = fmaf(vmm, wp[3 * 4 + 3], a00);
        a01 = fmaf(v0p, wp[1 * 4 + 0], a01);
        a01 = fmaf(v00, wp[1 * 4 + 2], a01);
        a01 = fmaf(vmp, wp[3 * 4 + 0], a01);
        a01 = fmaf(vm0, wp[3 * 4 + 2], a01);
        a10 = fmaf(vp0, wp[0 * 4 + 1], a10);
        a10 = fmaf(vpm, wp[0 * 4 + 3], a10);
        a10 = fmaf(v00, wp[2 * 4 + 1], a10);
        a10 = fmaf(v0m, wp[2 * 4 + 3], a10);
        a11 = fmaf(vpp, wp[0 * 4 + 0], a11);
        a11 = fmaf(vp0, wp[0 * 4 + 2], a11);
        a11 = fmaf(v0p, wp[2 * 4 + 0], a11);
        a11 = fmaf(v00, wp[2 * 4 + 2], a11);
    }

    float* __restrict__ outb = out + (size_t)b * 256 * 256;
    ((float2*)(outb + (size_t)(2 * i) * OW))[j] = make_float2(a00, a01);
    ((float2*)(outb + (size_t)(2 * i + 1) * OW))[j] = make_float2(a10, a11);
}

// VQ-GEMM (validated R9). DO NOT reorder any fmaf chain (R3).
__global__ __launch_bounds__(256) void vq_gemm(
    const float* __restrict__ h,    // (32,64,4096)
    const float* __restrict__ cb,   // (512,64) row-major (gather)
    const float* __restrict__ cbT,  // (64,512) dim-major (matmul)
    const float* __restrict__ ee,   // (512)
    float* __restrict__ q)          // (32,64,4096)
{
    __shared__ __align__(16) float As[64 * 128];
    __shared__ float xx_sh[128];
    __shared__ float pd[4 * 128];
    __shared__ int   pk[4 * 128];
    __shared__ int   bidx_sh[128];

    const int tid = threadIdx.x;
    const int tpx = tid & 63;
    const int w = __builtin_amdgcn_readfirstlane(tid >> 6);
    const int n0 = blockIdx.x * 128;
    const int b  = n0 >> 12;
    const int hw0 = n0 & 4095;

    const float* __restrict__ hb = h + (size_t)b * 64 * 4096 + hw0;
#pragma unroll
    for (int m = 0; m < 32; m++) {
        const int idx = m * 256 + tid;
        const int k = idx >> 7, p = idx & 127;
        As[idx] = hb[(size_t)k * 4096 + p];
    }
    __syncthreads();

    if (tid < 128) {
        float s = 0.0f;
#pragma unroll
        for (int i = 0; i < 64; i++) {
            const float v = As[i * 128 + tid];
            s = fmaf(v, v, s);
        }
        xx_sh[tid] = s;
    }
    __syncthreads();

    const float xx0 = xx_sh[tpx * 2];
    const float xx1 = xx_sh[tpx * 2 + 1];
    const int cwave = w * 128;

    float best0 = 3.402823466e+38f, best1 = 3.402823466e+38f;
    int bk0 = 0, bk1 = 0;

#pragma unroll 1
    for (int ch = 0; ch < 16; ch++) {
        const int cbase = cwave + ch * 8;
        float acc[8][2];
#pragma unroll
        for (int c = 0; c < 8; c++) { acc[c][0] = 0.0f; acc[c][1] = 0.0f; }

#pragma unroll 8
        for (int k = 0; k < 64; k++) {
            const float2 a2 = *(const float2*)(As + k * 128 + tpx * 2);
            const float* __restrict__ wk = cbT + (size_t)k * 512 + cbase;
#pragma unroll
            for (int c = 0; c < 8; c++) {
                const float wv = wk[c];
                acc[c][0] = fmaf(a2.x, wv, acc[c][0]);
                acc[c][1] = fmaf(a2.y, wv, acc[c][1]);
            }
        }
        const float* __restrict__ eep = ee + cbase;
#pragma unroll
        for (int c = 0; c < 8; c++) {
            const float eec = eep[c];
            const float d0 = xx0 - 2.0f * acc[c][0] + eec;
            const float d1 = xx1 - 2.0f * acc[c][1] + eec;
            if (d0 < best0) { best0 = d0; bk0 = cbase + c; }
            if (d1 < best1) { best1 = d1; bk1 = cbase + c; }
        }
    }

    pd[w * 128 + tpx * 2]     = best0;
    pd[w * 128 + tpx * 2 + 1] = best1;
    pk[w * 128 + tpx * 2]     = bk0;
    pk[w * 128 + tpx * 2 + 1] = bk1;
    __syncthreads();

    if (tid < 128) {
        float bd = pd[tid]; int bk = pk[tid];
#pragma unroll
        for (int ww = 1; ww < 4; ww++) {
            const float od = pd[ww * 128 + tid];
            if (od < bd) { bd = od; bk = pk[ww * 128 + tid]; }
        }
        bidx_sh[tid] = bk;
    }
    __syncthreads();

    {
        const int p  = tid & 127;
        const int d0 = (tid >> 7) * 32;
        const int bk = bidx_sh[p];
        const float4* __restrict__ cp4 = (const float4*)(cb + (size_t)bk * 64 + d0);
        float* __restrict__ qb = q + ((size_t)b * 64 + d0) * 4096 + hw0 + p;
#pragma unroll
        for (int i = 0; i < 8; i++) {
            const float4 v = cp4[i];
            qb[(size_t)(4 * i + 0) * 4096] = v.x;
            qb[(size_t)(4 * i + 1) * 4096] = v.y;
            qb[(size_t)(4 * i + 2) * 4096] = v.z;
            qb[(size_t)(4 * i + 3) * 4096] = v.w;
        }
    }
}

extern "C" void kernel_launch(void* const* d_in, const int* in_sizes, int n_in,
                              void* d_out, int out_size, void* d_ws, size_t ws_size,
                              hipStream_t stream) {
    const float* x      = (const float*)d_in[0];
    const float* w_e1   = (const float*)d_in[1];
    const float* b_e1   = (const float*)d_in[2];
    const float* w_e2   = (const float*)d_in[3];
    const float* b_e2   = (const float*)d_in[4];
    const float* w_er1a = (const float*)d_in[5];
    const float* w_er1b = (const float*)d_in[6];
    const float* w_er2a = (const float*)d_in[7];
    const float* w_er2b = (const float*)d_in[8];
    const float* w_pre  = (const float*)d_in[9];
    const float* b_pre  = (const float*)d_in[10];
    const float* cbk    = (const float*)d_in[11];
    const float* w_d1   = (const float*)d_in[12];
    const float* b_d1   = (const float*)d_in[13];
    const float* w_dr1a = (const float*)d_in[14];
    const float* w_dr1b = (const float*)d_in[15];
    const float* w_dr2a = (const float*)d_in[16];
    const float* w_dr2b = (const float*)d_in[17];
    const float* w_t1   = (const float*)d_in[18];
    const float* b_t1   = (const float*)d_in[19];
    const float* w_t2   = (const float*)d_in[20];
    const float* b_t2   = (const float*)d_in[21];
    float* out = (float*)d_out;

    float* A  = (float*)d_ws;            // 16777216 floats (scratch + t1 out)
    float* Bb = A  + 16777216;           // (32,64,64,64) = 8388608
    float* C  = Bb + 8388608;            // 4194304 (unused after fusion)
    float* D  = C  + 4194304;            // (32,64,64,64) = 8388608
    float* WR = D  + 8388608;            // repacked weights + cbT (221696)
    float* EE = WR + 221696;             // ee (512)

    float* r_e1  = WR;
    float* r_e2  = WR + 512;
    float* r_er1a = WR + 33280;
    float* r_er1b = WR + 51712;
    float* r_er2a = WR + 53760;
    float* r_er2b = WR + 72192;
    float* r_pre = WR + 74240;
    float* r_d1  = WR + 78336;
    float* r_dr1a = WR + 115200;
    float* r_dr1b = WR + 133632;
    float* r_dr2a = WR + 135680;
    float* r_dr2b = WR + 154112;
    float* r_t1  = WR + 156160;
    float* r_cbT = WR + 188928;

    const dim3 blk(256);
    const dim3 blk512(512);

    repack_all<<<dim3(866), blk, 0, stream>>>(
        w_e1, w_e2, w_er1a, w_er1b, w_er2a, w_er2b, w_pre, w_d1,
        w_dr1a, w_dr1b, w_dr2a, w_dr2b, w_t1, cbk, WR);
    vq_prep_ee<<<dim3(2), blk, 0, stream>>>(cbk, EE);

    // Encoder
    conv_gemm<32, 32, 1, 4, 2, 1, false, true, false, true>
        <<<dim3(2048, 1), blk, 0, stream>>>(x, r_e1, b_e1, nullptr, A,
                                            256, 256, 128, 128);
    conv4s2_tile<<<dim3(1024), blk512, 0, stream>>>(A, r_e2, b_e2, Bb);
    // er1: Bb -> A ; er2: A -> Bb (ping-pong avoids in-place halo race)
    res_tile<<<dim3(1024), blk512, 0, stream>>>(Bb, r_er1a, r_er1b, A);
    res_tile<<<dim3(1024), blk512, 0, stream>>>(A, r_er2a, r_er2b, Bb);
    // pre: stage-once 1x1
    conv1x1_tile<<<dim3(512), blk512, 0, stream>>>(Bb, r_pre, b_pre, D);
    // VQ
    vq_gemm<<<dim3(1024), blk, 0, stream>>>(D, cbk, r_cbT, EE, Bb);
    // Decoder
    conv3_tile<<<dim3(1024), blk512, 0, stream>>>(Bb, r_d1, b_d1, D);
    // dr1: D -> A ; dr2: A -> D
    res_tile<<<dim3(1024), blk512, 0, stream>>>(D, r_dr1a, r_dr1b, A);
    res_tile<<<dim3(1024), blk512, 0, stream>>>(A, r_dr2a, r_dr2b, D);
    // t1 stage-once: grid 512, both pr per block
    convt_tile<<<dim3(512), blk512, 0, stream>>>(D, r_t1, b_t1, A);
    // t2
    convt2_quad<<<dim3(64, 32), blk, 0, stream>>>(A, w_t2, b_t2, out, 32);
}

// Round 14
// 886.528 us; speedup vs baseline: 1.0536x; 1.0536x over previous
//
#include <hip/hip_runtime.h>
#include <hip/hip_bf16.h>

// ---------------------------------------------------------------------------
// VQ-VAE forward, fp32. NCHW.
// R29 = revert to R26 (best-measured: 891.8us). R27/R28 post-mortem: the
// px-split halved couts/thread (conv3 16->8, res conv1 8->4) while LDS
// reads/(ci,kh) stayed 3xb64 -> FMA:LDS-dword ratio halved -> res conv1
// went 24:12 (balanced) to 12:12 per wave-step; at 32 waves/CU the LDS
// demand (384 clk) = 2x per-SIMD VALU -> LDS-bound, occupancy gain
// cancelled; total 892->934. Conclusion: every config of this family sits
// ON the LDS/VALU balance line -- occupancy and per-thread co trade off
// through the LDS pipe. ~890us is this structure's balance point
// (confirmed from 6 directions: R15-R17 occupancy, R19/R22-R25 conflicts,
// R26 LDS size, R27/R28 grid supply).
// ---------------------------------------------------------------------------

__device__ __forceinline__ float rp_elem(const float* __restrict__ src,
                                         int i, int COUT, int CIN, int KK)
{
    const int co = i % COUT;
    const int t  = i / COUT;
    const int kk = t % KK;
    const int ci = t / KK;
    return src[(co * CIN + ci) * KK + kk];
}

// One kernel repacks all weights + codebook-transpose into WR.
__global__ __launch_bounds__(256) void repack_all(
    const float* __restrict__ e1,  const float* __restrict__ e2,
    const float* __restrict__ er1a, const float* __restrict__ er1b,
    const float* __restrict__ er2a, const float* __restrict__ er2b,
    const float* __restrict__ pre, const float* __restrict__ d1,
    const float* __restrict__ dr1a, const float* __restrict__ dr1b,
    const float* __restrict__ dr2a, const float* __restrict__ dr2b,
    const float* __restrict__ t1, const float* __restrict__ cb,
    float* __restrict__ WR)
{
    const int idx = blockIdx.x * 256 + threadIdx.x;
    if (idx >= 221696) return;
    float v;
    if      (idx < 512)    v = rp_elem(e1,   idx,          32,  1, 16);
    else if (idx < 33280)  v = rp_elem(e2,   idx - 512,    64, 32, 16);
    else if (idx < 51712)  v = rp_elem(er1a, idx - 33280,  32, 64,  9);
    else if (idx < 53760)  v = rp_elem(er1b, idx - 51712,  64, 32,  1);
    else if (idx < 72192)  v = rp_elem(er2a, idx - 53760,  32, 64,  9);
    else if (idx < 74240)  v = rp_elem(er2b, idx - 72192,  64, 32,  1);
    else if (idx < 78336)  v = rp_elem(pre,  idx - 74240,  64, 64,  1);
    else if (idx < 115200) v = rp_elem(d1,   idx - 78336,  64, 64,  9);
    else if (idx < 133632) v = rp_elem(dr1a, idx - 115200, 32, 64,  9);
    else if (idx < 135680) v = rp_elem(dr1b, idx - 133632, 64, 32,  1);
    else if (idx < 154112) v = rp_elem(dr2a, idx - 135680, 32, 64,  9);
    else if (idx < 156160) v = rp_elem(dr2b, idx - 154112, 64, 32,  1);
    else if (idx < 188928) {
        // t1: [pr][k2=ci*2+ta][q=pc*2+tb][co]
        const int i  = idx - 156160;
        const int co = i & 31;
        const int q  = (i >> 5) & 3;
        const int k2 = (i >> 7) & 127;
        const int pr = i >> 14;
        const int pc = q >> 1, tb = q & 1;
        const int ci = k2 >> 1, ta = k2 & 1;
        const int kh = (1 - pr) + 2 * ta, kw = (1 - pc) + 2 * tb;
        v = t1[((ci * 32 + co) * 4 + kh) * 4 + kw];
    } else {
        const int i = idx - 188928;           // cbT: [dim][code]
        const int code = i & 511;
        const int dim  = i >> 9;
        v = cb[code * 64 + dim];
    }
    WR[idx] = v;
}

// ee[k] = sum_i cb[k][i]^2, exact ascending fmaf chain (matches reference).
__global__ __launch_bounds__(256) void vq_prep_ee(
    const float* __restrict__ cb, float* __restrict__ ee)
{
    const int k = blockIdx.x * 256 + threadIdx.x;  // grid(2) -> k < 512
    const float* __restrict__ cp = cb + (size_t)k * 64;
    float s = 0.0f;
#pragma unroll
    for (int i = 0; i < 64; i++) s = fmaf(cp[i], cp[i], s);
    ee[k] = s;
}

// GEMM-form conv (validated R13) — still used by e1.
template<int CTOT, int CPB, int CIN, int K, int S, int PAD,
         bool RELU_IN, bool HAS_BIAS, bool RESID, bool RELU_OUT>
__global__ __launch_bounds__(256) void conv_gemm(
    const float* __restrict__ in, const float* __restrict__ wr,
    const float* __restrict__ bias, const float* __restrict__ resid,
    float* __restrict__ out,
    int H, int W, int OH, int OW)
{
    constexpr int KK  = K * K;
    constexpr int CIC = (K == 1) ? 8 : 1;
    constexpr int TS  = (K == 4) ? 2 : 1;
    constexpr int KC  = CIC * KK / TS;
    constexpr int NCH = (CIN * TS) / CIC;
    constexpr int NT  = 256;
    constexpr int CPTHD = CPB / 4;
    __shared__ __align__(16) float As[2][KC * NT];

    const int tid = threadIdx.x;
    const int tpx = tid & 63;
    const int tco = __builtin_amdgcn_readfirstlane(tid >> 6);
    const int co0 = blockIdx.y * CPB + tco * CPTHD;

    const int ohow = OH * OW;
    const int n_st = blockIdx.x * NT + tid;
    const int b_st = n_st / ohow;
    const int hw_s = n_st % ohow;
    const int ih0 = (hw_s / OW) * S - PAD;
    const int iw0 = (hw_s % OW) * S - PAD;
    const float* __restrict__ inb = in + (size_t)b_st * CIN * H * W;

    float acc[CPTHD][4];
#pragma unroll
    for (int c = 0; c < CPTHD; c++) {
        const float bz = HAS_BIAS ? bias[co0 + c] : 0.0f;
#pragma unroll
        for (int q = 0; q < 4; q++) acc[c][q] = bz;
    }

    float pf[KC];
    auto stage_load = [&](int ch) {
#pragma unroll
        for (int t = 0; t < KC; t++) {
            int ci, kh, kw;
            if constexpr (K == 1) {
                ci = ch * 8 + t; kh = 0; kw = 0;
            } else if constexpr (K == 3) {
                ci = ch; kh = t / 3; kw = t % 3;
            } else {                                 // K == 4, TS = 2
                ci = ch >> 1;
                const int kk = ((ch & 1) << 3) + t;
                kh = kk >> 2; kw = kk & 3;
            }
            const int ih = ih0 + kh, iw = iw0 + kw;
            float v = 0.0f;
            if (ih >= 0 && ih < H && iw >= 0 && iw < W)
                v = inb[(size_t)ci * H * W + ih * W + iw];
            if (RELU_IN) v = fmaxf(v, 0.0f);
            pf[t] = v;
        }
    };

    stage_load(0);
#pragma unroll
    for (int t = 0; t < KC; t++) As[0][t * NT + tid] = pf[t];
    __syncthreads();

#pragma unroll 2
    for (int c = 0; c < NCH; c++) {
        const int cur = c & 1;
        if (c + 1 < NCH) stage_load(c + 1);

#pragma unroll
        for (int t = 0; t < KC; t++) {
            const float4 a4 = *(const float4*)(As[cur] + t * NT + tpx * 4);
            const float* __restrict__ wk =
                wr + (size_t)(c * KC + t) * CTOT + co0;
#pragma unroll
            for (int cc = 0; cc < CPTHD; cc++) {
                const float w = wk[cc];
                acc[cc][0] = fmaf(a4.x, w, acc[cc][0]);
                acc[cc][1] = fmaf(a4.y, w, acc[cc][1]);
                acc[cc][2] = fmaf(a4.z, w, acc[cc][2]);
                acc[cc][3] = fmaf(a4.w, w, acc[cc][3]);
            }
        }

        if (c + 1 < NCH) {
#pragma unroll
            for (int t = 0; t < KC; t++) As[1 - cur][t * NT + tid] = pf[t];
        }
        __syncthreads();
    }

    const int n_c  = blockIdx.x * NT + tpx * 4;
    const int b_c  = n_c / ohow;
    const int hw_c = n_c % ohow;
    float* __restrict__ op = out + (size_t)b_c * CTOT * ohow + hw_c;
    const float* __restrict__ rp =
        RESID ? (resid + (size_t)b_c * CTOT * ohow + hw_c) : nullptr;
#pragma unroll
    for (int c = 0; c < CPTHD; c++) {
        const size_t off = (size_t)(co0 + c) * ohow;
        float4 r = make_float4(acc[c][0], acc[c][1], acc[c][2], acc[c][3]);
        if (RESID) {
            const float4 rv = *(const float4*)(rp + off);
            r.x += rv.x; r.y += rv.y; r.z += rv.z; r.w += rv.w;
        }
        if (RELU_OUT) {
            r.x = fmaxf(r.x, 0.f); r.y = fmaxf(r.y, 0.f);
            r.z = fmaxf(r.z, 0.f); r.w = fmaxf(r.w, 0.f);
        }
        *(float4*)(op + off) = r;
    }
}

// Fused residual block, R26: 68-col tile (51KB), 256 px/block, grid 512.
// conv1: 8co x 2px/thread; conv2: 16co x 2px. (validated R26: 891.8us)
__global__ __launch_bounds__(512, 4) void res_tile(
    const float* __restrict__ in, const float* __restrict__ wr1,
    const float* __restrict__ wr2, float* __restrict__ out)
{
    // tile: [ci<32][r6<6][68] = 13056 floats (51KB); mid[32][256] overlays.
    __shared__ __align__(16) float S[13056];

    const int tid = threadIdx.x;
    const int p   = tid & 127;                                  // px-pair
    const int cog = __builtin_amdgcn_readfirstlane(tid >> 7);   // 0..3
    const int a   = p >> 5;                // px row in block (0..3)
    const int c0  = (p & 31) * 2;          // px col base (0,2,..,62)

    const int n0   = blockIdx.x * 256;
    const int b    = n0 >> 12;
    const int row0 = (n0 & 4095) >> 6;     // 4 rows of 64
    const float* __restrict__ inb = in + (size_t)b * 64 * 4096;

    // zero halo cols {0,1,66,67} of each of the 192 rows (written once;
    // commits touch cols 2..65 only).
    if (tid < 192) {
        float* __restrict__ rp0 = S + tid * 68;
        *(float2*)(rp0)      = make_float2(0.f, 0.f);
        *(float2*)(rp0 + 66) = make_float2(0.f, 0.f);
    }

    float4 pf4[6];
    auto stage_issue = [&](int half) {
#pragma unroll
        for (int m = 0; m < 6; m++) {
            const int f4 = m * 512 + tid;        // 0..3071
            const int ci  = f4 / 96;
            const int rem = f4 - ci * 96;
            const int r6  = rem >> 4;            // 0..5
            const int s   = rem & 15;            // 0..15, iw = 4s..4s+3
            const int ih  = row0 + r6 - 1;
            float4 v = make_float4(0.f, 0.f, 0.f, 0.f);
            if (ih >= 0 && ih < 64)
                v = *(const float4*)(inb + (size_t)(half * 32 + ci) * 4096
                                     + ih * 64 + s * 4);
            pf4[m] = v;
        }
    };
    auto stage_commit = [&]() {
#pragma unroll
        for (int m = 0; m < 6; m++) {
            const int f4 = m * 512 + tid;
            const int ci  = f4 / 96;
            const int rem = f4 - ci * 96;
            const int r6  = rem >> 4;
            const int s   = rem & 15;
            float4 v = pf4[m];
            v.x = fmaxf(v.x, 0.f); v.y = fmaxf(v.y, 0.f);
            v.z = fmaxf(v.z, 0.f); v.w = fmaxf(v.w, 0.f);
            float* __restrict__ rowp = S + (ci * 6 + r6) * 68 + s * 4;
            *(float2*)(rowp + 2) = make_float2(v.x, v.y);
            *(float2*)(rowp + 4) = make_float2(v.z, v.w);
        }
    };

    const int co1 = cog * 8;
    float acc1[8][2];
#pragma unroll
    for (int c = 0; c < 8; c++) { acc1[c][0] = 0.0f; acc1[c][1] = 0.0f; }

    auto conv1_half = [&](int h) {
#pragma unroll 2
        for (int c = 0; c < 32; c++) {
            const float* __restrict__ wb =
                wr1 + (size_t)((h * 32 + c) * 9) * 32 + co1;
#pragma unroll
            for (int kh = 0; kh < 3; kh++) {
                const float* __restrict__ tp =
                    S + c * 408 + (a + kh) * 68 + 2 + c0;
                const float2 L = *(const float2*)(tp - 2);
                const float2 M = *(const float2*)(tp);
                const float2 R = *(const float2*)(tp + 2);
                const float xm = L.y;
                const float x0 = M.x;
                const float x1 = M.y;
                const float x2 = R.x;
                const float* __restrict__ wk = wb + (size_t)(kh * 3) * 32;
#pragma unroll
                for (int cc = 0; cc < 8; cc++) {     // kw = 0
                    const float w = wk[cc];
                    acc1[cc][0] = fmaf(xm, w, acc1[cc][0]);
                    acc1[cc][1] = fmaf(x0, w, acc1[cc][1]);
                }
#pragma unroll
                for (int cc = 0; cc < 8; cc++) {     // kw = 1
                    const float w = wk[32 + cc];
                    acc1[cc][0] = fmaf(x0, w, acc1[cc][0]);
                    acc1[cc][1] = fmaf(x1, w, acc1[cc][1]);
                }
#pragma unroll
                for (int cc = 0; cc < 8; cc++) {     // kw = 2
                    const float w = wk[64 + cc];
                    acc1[cc][0] = fmaf(x1, w, acc1[cc][0]);
                    acc1[cc][1] = fmaf(x2, w, acc1[cc][1]);
                }
            }
        }
    };

    stage_issue(0);
    stage_commit();
    __syncthreads();
    stage_issue(1);
    conv1_half(0);
    __syncthreads();
    stage_commit();
    __syncthreads();
    conv1_half(1);
    __syncthreads();

    // mid[co][px] (32x256 = 8192 floats) overlays tile region.
#pragma unroll
    for (int cc = 0; cc < 8; cc++)
        *(float2*)(S + (co1 + cc) * 256 + p * 2) =
            make_float2(acc1[cc][0], acc1[cc][1]);
    __syncthreads();

    const int co2 = cog * 16;
    float acc2[16][2];
#pragma unroll
    for (int c = 0; c < 16; c++) { acc2[c][0] = 0.0f; acc2[c][1] = 0.0f; }

#pragma unroll 4
    for (int k = 0; k < 32; k++) {
        float2 m2 = *(const float2*)(S + k * 256 + p * 2);
        m2.x = fmaxf(m2.x, 0.f);
        m2.y = fmaxf(m2.y, 0.f);
        const float* __restrict__ wk = wr2 + (size_t)k * 64 + co2;
#pragma unroll
        for (int cc = 0; cc < 16; cc++) {
            const float w = wk[cc];
            acc2[cc][0] = fmaf(m2.x, w, acc2[cc][0]);
            acc2[cc][1] = fmaf(m2.y, w, acc2[cc][1]);
        }
    }

    const int hw = (n0 & 4095) + p * 2;
    const float* __restrict__ rp = inb + hw;
    float* __restrict__ op = out + (size_t)b * 64 * 4096 + hw;
#pragma unroll
    for (int cc = 0; cc < 16; cc++) {
        const size_t off = (size_t)(co2 + cc) * 4096;
        const float2 rv = *(const float2*)(rp + off);
        *(float2*)(op + off) =
            make_float2(acc2[cc][0] + rv.x, acc2[cc][1] + rv.y);
    }
}

// R26: stage-once 3x3 conv 64ci->64co (d1), 68-col tile (51KB), grid 512.
// 16co x 2px/thread. (validated R26)
__global__ __launch_bounds__(512, 4) void conv3_tile(
    const float* __restrict__ in, const float* __restrict__ wr,
    const float* __restrict__ bias, float* __restrict__ out)
{
    __shared__ __align__(16) float S[13056];   // [ci<32][6][68], 51KB

    const int tid = threadIdx.x;
    const int p   = tid & 127;
    const int cog = __builtin_amdgcn_readfirstlane(tid >> 7);   // 0..3
    const int a   = p >> 5;
    const int c0  = (p & 31) * 2;

    const int n0   = blockIdx.x * 256;
    const int b    = n0 >> 12;
    const int row0 = (n0 & 4095) >> 6;
    const float* __restrict__ inb = in + (size_t)b * 64 * 4096;

    if (tid < 192) {
        float* __restrict__ rp0 = S + tid * 68;
        *(float2*)(rp0)      = make_float2(0.f, 0.f);
        *(float2*)(rp0 + 66) = make_float2(0.f, 0.f);
    }

    float4 pf4[6];
    auto stage_issue = [&](int half) {
#pragma unroll
        for (int m = 0; m < 6; m++) {
            const int f4 = m * 512 + tid;
            const int ci  = f4 / 96;
            const int rem = f4 - ci * 96;
            const int r6  = rem >> 4;
            const int s   = rem & 15;
            const int ih  = row0 + r6 - 1;
            float4 v = make_float4(0.f, 0.f, 0.f, 0.f);
            if (ih >= 0 && ih < 64)
                v = *(const float4*)(inb + (size_t)(half * 32 + ci) * 4096
                                     + ih * 64 + s * 4);
            pf4[m] = v;
        }
    };
    auto stage_commit = [&]() {
#pragma unroll
        for (int m = 0; m < 6; m++) {
            const int f4 = m * 512 + tid;
            const int ci  = f4 / 96;
            const int rem = f4 - ci * 96;
            const int r6  = rem >> 4;
            const int s   = rem & 15;
            const float4 v = pf4[m];
            float* __restrict__ rowp = S + (ci * 6 + r6) * 68 + s * 4;
            *(float2*)(rowp + 2) = make_float2(v.x, v.y);   // no relu
            *(float2*)(rowp + 4) = make_float2(v.z, v.w);
        }
    };

    const int co1 = cog * 16;
    float acc[16][2];
#pragma unroll
    for (int cc = 0; cc < 16; cc++) {
        const float bz = bias[co1 + cc];
        acc[cc][0] = bz; acc[cc][1] = bz;
    }

    auto conv_half = [&](int h) {
#pragma unroll 2
        for (int c = 0; c < 32; c++) {
            const float* __restrict__ wb =
                wr + (size_t)((h * 32 + c) * 9) * 64 + co1;
#pragma unroll
            for (int kh = 0; kh < 3; kh++) {
                const float* __restrict__ tp =
                    S + c * 408 + (a + kh) * 68 + 2 + c0;
                const float2 L = *(const float2*)(tp - 2);
                const float2 M = *(const float2*)(tp);
                const float2 R = *(const float2*)(tp + 2);
                const float xm = L.y;
                const float x0 = M.x;
                const float x1 = M.y;
                const float x2 = R.x;
                const float* __restrict__ wk = wb + (size_t)(kh * 3) * 64;
#pragma unroll
                for (int cc = 0; cc < 16; cc++) {    // kw = 0
                    const float w = wk[cc];
                    acc[cc][0] = fmaf(xm, w, acc[cc][0]);
                    acc[cc][1] = fmaf(x0, w, acc[cc][1]);
                }
#pragma unroll
                for (int cc = 0; cc < 16; cc++) {    // kw = 1
                    const float w = wk[64 + cc];
                    acc[cc][0] = fmaf(x0, w, acc[cc][0]);
                    acc[cc][1] = fmaf(x1, w, acc[cc][1]);
                }
#pragma unroll
                for (int cc = 0; cc < 16; cc++) {    // kw = 2
                    const float w = wk[128 + cc];
                    acc[cc][0] = fmaf(x1, w, acc[cc][0]);
                    acc[cc][1] = fmaf(x2, w, acc[cc][1]);
                }
            }
        }
    };

    stage_issue(0);
    stage_commit();
    __syncthreads();
    stage_issue(1);
    conv_half(0);
    __syncthreads();
    stage_commit();
    __syncthreads();
    conv_half(1);

    const int hw = (n0 & 4095) + p * 2;
    float* __restrict__ op = out + (size_t)b * 64 * 4096 + hw;
#pragma unroll
    for (int cc = 0; cc < 16; cc++)
        *(float2*)(op + (size_t)(co1 + cc) * 4096) =
            make_float2(acc[cc][0], acc[cc][1]);
}

// R25: stage-once stride-2 4x4 conv 32ci->64co (e2), deinterleaved LDS.
// (validated R25 — e2 dropped out of top-5)
__global__ __launch_bounds__(512, 4) void conv4s2_tile(
    const float* __restrict__ in, const float* __restrict__ wr,
    const float* __restrict__ bias, float* __restrict__ out)
{
    // [ci<16][r6<6][E 68 | O 68] = 13056 floats, 51KB
    __shared__ __align__(16) float S[13056];

    const int tid = threadIdx.x;
    const int p   = tid & 127;                                  // out px
    const int cog = __builtin_amdgcn_readfirstlane(tid >> 7);   // 0..3
    const int a   = p >> 6;                 // out row (0..1)
    const int j   = p & 63;                 // out col

    const int n0   = blockIdx.x * 128;
    const int b    = n0 >> 12;
    const int row0 = (n0 & 4095) >> 6;      // 2 out rows of 64
    const float* __restrict__ inb = in + (size_t)b * 32 * 16384;

    float4 pf4[7];
    auto stage_issue = [&](int half) {
#pragma unroll
        for (int m = 0; m < 7; m++) {
            const int f4 = m * 512 + tid;
            float4 v = make_float4(0.f, 0.f, 0.f, 0.f);
            if (f4 < 3264) {
                const int ci  = f4 / 204;
                const int rem = f4 - ci * 204;
                const int r6  = rem / 34;
                const int s   = rem - r6 * 34;
                const int ih  = 2 * row0 - 1 + r6;
                if (ih >= 0 && ih < 128 && s >= 1 && s <= 32)
                    v = *(const float4*)(inb + (size_t)(half * 16 + ci) * 16384
                                         + ih * 128 + (s - 1) * 4);
            }
            pf4[m] = v;
        }
    };
    auto stage_commit = [&]() {
#pragma unroll
        for (int m = 0; m < 7; m++) {
            const int f4 = m * 512 + tid;
            if (f4 < 3264) {
                const int ci  = f4 / 204;
                const int rem = f4 - ci * 204;
                const int r6  = rem / 34;
                const int s   = rem - r6 * 34;
                const float4 v = pf4[m];
                float* __restrict__ rowp = S + (ci * 6 + r6) * 136;
                *(float2*)(rowp + 2 * s)      = make_float2(v.x, v.z);  // E
                *(float2*)(rowp + 68 + 2 * s) = make_float2(v.y, v.w);  // O
            }
        }
    };

    const int co1 = cog * 16;
    float acc[16];
#pragma unroll
    for (int cc = 0; cc < 16; cc++) acc[cc] = bias[co1 + cc];

    auto conv_half = [&](int h) {
#pragma unroll 2
        for (int c = 0; c < 16; c++) {
            const float* __restrict__ wb =
                wr + (size_t)((h * 16 + c) * 16) * 64 + co1;
#pragma unroll
            for (int kh = 0; kh < 4; kh++) {
                const float* __restrict__ rowp =
                    S + (c * 6 + 2 * a + kh) * 136;
                const float e0 = rowp[j + 2];        // iw = 2j
                const float e1 = rowp[j + 3];        // iw = 2j+2
                const float o0 = rowp[68 + j + 1];   // iw = 2j-1
                const float o1 = rowp[68 + j + 2];   // iw = 2j+1
                const float* __restrict__ wk = wb + (size_t)(kh * 4) * 64;
#pragma unroll
                for (int cc = 0; cc < 16; cc++)      // kw = 0 (iw 2j-1)
                    acc[cc] = fmaf(o0, wk[cc], acc[cc]);
#pragma unroll
                for (int cc = 0; cc < 16; cc++)      // kw = 1 (iw 2j)
                    acc[cc] = fmaf(e0, wk[64 + cc], acc[cc]);
#pragma unroll
                for (int cc = 0; cc < 16; cc++)      // kw = 2 (iw 2j+1)
                    acc[cc] = fmaf(o1, wk[128 + cc], acc[cc]);
#pragma unroll
                for (int cc = 0; cc < 16; cc++)      // kw = 3 (iw 2j+2)
                    acc[cc] = fmaf(e1, wk[192 + cc], acc[cc]);
            }
        }
    };

    stage_issue(0);
    stage_commit();
    __syncthreads();
    stage_issue(1);
    conv_half(0);
    __syncthreads();
    stage_commit();
    __syncthreads();
    conv_half(1);

    const int hw = (n0 & 4095) + a * 64 + j;
    float* __restrict__ op = out + (size_t)b * 64 * 4096 + hw;
#pragma unroll
    for (int cc = 0; cc < 16; cc++)
        op[(size_t)(co1 + cc) * 4096] = acc[cc];
}

// R22: stage-once 1x1 conv 64ci->64co (pre). (validated)
__global__ __launch_bounds__(512, 4) void conv1x1_tile(
    const float* __restrict__ in, const float* __restrict__ wr,
    const float* __restrict__ bias, float* __restrict__ out)
{
    __shared__ __align__(16) float S[8192];    // [ci<32][256px], 32KB

    const int tid = threadIdx.x;
    const int p   = tid & 127;                                  // px-pair
    const int cog = __builtin_amdgcn_readfirstlane(tid >> 7);   // 0..3

    const int n0  = blockIdx.x * 256;
    const int b   = n0 >> 12;
    const int hw0 = n0 & 4095;
    const float* __restrict__ inb = in + (size_t)b * 64 * 4096 + hw0;

    float4 pf4[4];
    auto stage_issue = [&](int half) {
#pragma unroll
        for (int m = 0; m < 4; m++) {
            const int f4 = m * 512 + tid;        // 0..2047
            const int ci = f4 >> 6;
            const int c4 = f4 & 63;
            pf4[m] = *(const float4*)(inb + (size_t)(half * 32 + ci) * 4096
                                      + c4 * 4);
        }
    };
    auto stage_commit = [&]() {
#pragma unroll
        for (int m = 0; m < 4; m++) {
            const int f4 = m * 512 + tid;
            *(float4*)(S + f4 * 4) = pf4[m];
        }
    };

    const int co1 = cog * 16;
    float acc[16][2];
#pragma unroll
    for (int cc = 0; cc < 16; cc++) {
        const float bz = bias[co1 + cc];
        acc[cc][0] = bz; acc[cc][1] = bz;
    }

    auto conv_half = [&](int h) {
#pragma unroll 4
        for (int c = 0; c < 32; c++) {
            const float2 x = *(const float2*)(S + c * 256 + p * 2);
            const float* __restrict__ wk =
                wr + (size_t)(h * 32 + c) * 64 + co1;
#pragma unroll
            for (int cc = 0; cc < 16; cc++) {
                const float w = wk[cc];
                acc[cc][0] = fmaf(x.x, w, acc[cc][0]);
                acc[cc][1] = fmaf(x.y, w, acc[cc][1]);
            }
        }
    };

    stage_issue(0);
    stage_commit();
    __syncthreads();
    stage_issue(1);
    conv_half(0);
    __syncthreads();
    stage_commit();
    __syncthreads();
    conv_half(1);

    float* __restrict__ op = out + (size_t)b * 64 * 4096 + hw0 + p * 2;
#pragma unroll
    for (int cc = 0; cc < 16; cc++)
        *(float2*)(op + (size_t)(co1 + cc) * 4096) =
            make_float2(acc[cc][0], acc[cc][1]);
}

// R26: stage-once transposed conv t1, 68-col tile (51KB). (validated)
__global__ __launch_bounds__(512, 4) void convt_tile(
    const float* __restrict__ in, const float* __restrict__ wr,
    const float* __restrict__ bias, float* __restrict__ out)
{
    __shared__ __align__(16) float S[13056];   // [ci<32][6][68], 51KB

    const int tid = threadIdx.x;
    const int p   = tid & 127;                                  // px-pair
    const int cog = __builtin_amdgcn_readfirstlane(tid >> 7);   // 0..3
    const int a   = p >> 5;                 // input row in block (0..3)
    const int c0  = (p & 31) * 2;           // input col base (0,2,..,62)

    const int n0   = blockIdx.x * 256;      // 256 input px = 4 rows
    const int b    = n0 >> 12;
    const int row0 = (n0 & 4095) >> 6;
    const float* __restrict__ inb = in + (size_t)b * 64 * 4096;

    if (tid < 192) {
        float* __restrict__ rp0 = S + tid * 68;
        *(float2*)(rp0)      = make_float2(0.f, 0.f);
        *(float2*)(rp0 + 66) = make_float2(0.f, 0.f);
    }

    float4 pf4[6];
    auto stage_issue = [&](int half) {
#pragma unroll
        for (int m = 0; m < 6; m++) {
            const int f4 = m * 512 + tid;
            const int ci  = f4 / 96;
            const int rem = f4 - ci * 96;
            const int r6  = rem >> 4;
            const int s   = rem & 15;
            const int ih  = row0 + r6 - 1;
            float4 v = make_float4(0.f, 0.f, 0.f, 0.f);
            if (ih >= 0 && ih < 64)
                v = *(const float4*)(inb + (size_t)(half * 32 + ci) * 4096
                                     + ih * 64 + s * 4);
            pf4[m] = v;
        }
    };
    auto stage_commit = [&]() {
#pragma unroll
        for (int m = 0; m < 6; m++) {
            const int f4 = m * 512 + tid;
            const int ci  = f4 / 96;
            const int rem = f4 - ci * 96;
            const int r6  = rem >> 4;
            const int s   = rem & 15;
            const float4 v = pf4[m];
            float* __restrict__ rowp = S + (ci * 6 + r6) * 68 + s * 4;
            *(float2*)(rowp + 2) = make_float2(v.x, v.y);   // no relu
            *(float2*)(rowp + 4) = make_float2(v.z, v.w);
        }
    };

    const int co1 = cog * 8;
    // acc[co][px][pc][pr]
    float acc[8][2][2][2];
#pragma unroll
    for (int cc = 0; cc < 8; cc++) {
        const float bz = bias[co1 + cc];
#pragma unroll
        for (int px = 0; px < 2; px++)
#pragma unroll
            for (int pc = 0; pc < 2; pc++) {
                acc[cc][px][pc][0] = bz;
                acc[cc][px][pc][1] = bz;
            }
    }

    auto conv_half = [&](int h) {
#pragma unroll 2
        for (int c = 0; c < 32; c++) {
            const int ci = h * 32 + c;
            float X[3][4];
#pragma unroll
            for (int r = 0; r < 3; r++) {
                const float* __restrict__ tp =
                    S + c * 408 + (a + r) * 68 + 2 + c0;
                const float2 L = *(const float2*)(tp - 2);
                const float2 M = *(const float2*)(tp);
                const float2 R = *(const float2*)(tp + 2);
                X[r][0] = L.y; X[r][1] = M.x; X[r][2] = M.y; X[r][3] = R.x;
            }
            const float* __restrict__ wb = wr + (size_t)(ci * 2) * 128 + co1;
#pragma unroll
            for (int ta = 0; ta < 2; ta++) {
                const float* X0 = X[1 - ta];
                const float* X1 = X[2 - ta];
                const float* __restrict__ wt = wb + ta * 128;
#pragma unroll
                for (int tb = 0; tb < 2; tb++) {
#pragma unroll
                    for (int pc = 0; pc < 2; pc++) {
                        const int m = pc - tb + 1;   // 0..2
                        const float* __restrict__ w0 = wt + (pc * 2 + tb) * 32;
                        const float* __restrict__ w1 = w0 + 16384;
#pragma unroll
                        for (int cc = 0; cc < 8; cc++) {
                            const float wv0 = w0[cc];
                            const float wv1 = w1[cc];
                            acc[cc][0][pc][0] =
                                fmaf(X0[m],     wv0, acc[cc][0][pc][0]);
                            acc[cc][1][pc][0] =
                                fmaf(X0[m + 1], wv0, acc[cc][1][pc][0]);
                            acc[cc][0][pc][1] =
                                fmaf(X1[m],     wv1, acc[cc][0][pc][1]);
                            acc[cc][1][pc][1] =
                                fmaf(X1[m + 1], wv1, acc[cc][1][pc][1]);
                        }
                    }
                }
            }
        }
    };

    stage_issue(0);
    stage_commit();
    __syncthreads();
    stage_issue(1);
    conv_half(0);
    __syncthreads();
    stage_commit();
    __syncthreads();
    conv_half(1);

    const int i = row0 + a;
    float* __restrict__ ob =
        out + (size_t)b * 32 * 16384 + (size_t)(2 * i) * 128 + 2 * c0;
#pragma unroll
    for (int cc = 0; cc < 8; cc++) {
        float* __restrict__ o = ob + (size_t)(co1 + cc) * 16384;
#pragma unroll
        for (int pr = 0; pr < 2; pr++) {
            const float4 v = make_float4(
                fmaxf(acc[cc][0][0][pr], 0.f), fmaxf(acc[cc][0][1][pr], 0.f),
                fmaxf(acc[cc][1][0][pr], 0.f), fmaxf(acc[cc][1][1][pr], 0.f));
            *(float4*)(o + (size_t)pr * 128) = v;
        }
    }
}

// Final transposed conv (32 -> 1). (validated)
__global__ __launch_bounds__(256) void convt2_quad(
    const float* __restrict__ in, const float* __restrict__ w,
    const float* __restrict__ bias, float* __restrict__ out, int B)
{
    const int IH = 128, IW = 128, CIN = 32, OW = 256;
    const int j = threadIdx.x & 127;
    const int i = (blockIdx.x << 1) + (threadIdx.x >> 7);
    const int b = blockIdx.y;

    const float* __restrict__ inb = in + (size_t)b * CIN * IH * IW;
    const float bz = bias[0];
    float a00 = bz, a01 = bz, a10 = bz, a11 = bz;

    const bool okm = (i > 0);
    const bool okp = (i < IH - 1);
    const bool olm = (j > 0);
    const bool olp = (j < IW - 1);

#pragma unroll 4
    for (int ci = 0; ci < CIN; ci++) {
        const float* __restrict__ p = inb + ((size_t)ci * IH + i) * IW + j;
        const float* __restrict__ wp = w + ci * 16;
        const float vmm = (okm && olm) ? p[-IW - 1] : 0.f;
        const float vm0 = okm ? p[-IW] : 0.f;
        const float vmp = (okm && olp) ? p[-IW + 1] : 0.f;
        const float v0m = olm ? p[-1] : 0.f;
        const float v00 = p[0];
        const float v0p = olp ? p[1] : 0.f;
        const float vpm = (okp && olm) ? p[IW - 1] : 0.f;
        const float vp0 = okp ? p[IW] : 0.f;
        const float vpp = (okp && olp) ? p[IW + 1] : 0.f;
        a00 = fmaf(v00, wp[1 * 4 + 1], a00);
        a00 = fmaf(v0m, wp[1 * 4 + 3], a00);
        a00 = fmaf(vm0, wp[3 * 4 + 1], a00);
        a00 = fmaf(vmm, wp[3 * 4 + 3], a00);
        a01 = fmaf(v0p, wp[1 * 4 + 0], a01);
        a01 = fmaf(v00, wp[1 * 4 + 2], a01);
        a01 = fmaf(vmp, wp[3 * 4 + 0], a01);
        a01 = fmaf(vm0, wp[3 * 4 + 2], a01);
        a10 = fmaf(vp0, wp[0 * 4 + 1], a10);
        a10 = fmaf(vpm, wp[0 * 4 + 3], a10);
        a10 = fmaf(v00, wp[2 * 4 + 1], a10);
        a10 = fmaf(v0m, wp[2 * 4 + 3], a10);
        a11 = fmaf(vpp, wp[0 * 4 + 0], a11);
        a11 = fmaf(vp0, wp[0 * 4 + 2], a11);
        a11 = fmaf(v0p, wp[2 * 4 + 0], a11);
        a11 = fmaf(v00, wp[2 * 4 + 2], a11);
    }

    float* __restrict__ outb = out + (size_t)b * 256 * 256;
    ((float2*)(outb + (size_t)(2 * i) * OW))[j] = make_float2(a00, a01);
    ((float2*)(outb + (size_t)(2 * i + 1) * OW))[j] = make_float2(a10, a11);
}

// VQ-GEMM (validated R9). DO NOT reorder any fmaf chain (R3).
__global__ __launch_bounds__(256) void vq_gemm(
    const float* __restrict__ h,    // (32,64,4096)
    const float* __restrict__ cb,   // (512,64) row-major (gather)
    const float* __restrict__ cbT,  // (64,512) dim-major (matmul)
    const float* __restrict__ ee,   // (512)
    float* __restrict__ q)          // (32,64,4096)
{
    __shared__ __align__(16) float As[64 * 128];
    __shared__ float xx_sh[128];
    __shared__ float pd[4 * 128];
    __shared__ int   pk[4 * 128];
    __shared__ int   bidx_sh[128];

    const int tid = threadIdx.x;
    const int tpx = tid & 63;
    const int w = __builtin_amdgcn_readfirstlane(tid >> 6);
    const int n0 = blockIdx.x * 128;
    const int b  = n0 >> 12;
    const int hw0 = n0 & 4095;

    const float* __restrict__ hb = h + (size_t)b * 64 * 4096 + hw0;
#pragma unroll
    for (int m = 0; m < 32; m++) {
        const int idx = m * 256 + tid;
        const int k = idx >> 7, p = idx & 127;
        As[idx] = hb[(size_t)k * 4096 + p];
    }
    __syncthreads();

    if (tid < 128) {
        float s = 0.0f;
#pragma unroll
        for (int i = 0; i < 64; i++) {
            const float v = As[i * 128 + tid];
            s = fmaf(v, v, s);
        }
        xx_sh[tid] = s;
    }
    __syncthreads();

    const float xx0 = xx_sh[tpx * 2];
    const float xx1 = xx_sh[tpx * 2 + 1];
    const int cwave = w * 128;

    float best0 = 3.402823466e+38f, best1 = 3.402823466e+38f;
    int bk0 = 0, bk1 = 0;

#pragma unroll 1
    for (int ch = 0; ch < 16; ch++) {
        const int cbase = cwave + ch * 8;
        float acc[8][2];
#pragma unroll
        for (int c = 0; c < 8; c++) { acc[c][0] = 0.0f; acc[c][1] = 0.0f; }

#pragma unroll 8
        for (int k = 0; k < 64; k++) {
            const float2 a2 = *(const float2*)(As + k * 128 + tpx * 2);
            const float* __restrict__ wk = cbT + (size_t)k * 512 + cbase;
#pragma unroll
            for (int c = 0; c < 8; c++) {
                const float wv = wk[c];
                acc[c][0] = fmaf(a2.x, wv, acc[c][0]);
                acc[c][1] = fmaf(a2.y, wv, acc[c][1]);
            }
        }
        const float* __restrict__ eep = ee + cbase;
#pragma unroll
        for (int c = 0; c < 8; c++) {
            const float eec = eep[c];
            const float d0 = xx0 - 2.0f * acc[c][0] + eec;
            const float d1 = xx1 - 2.0f * acc[c][1] + eec;
            if (d0 < best0) { best0 = d0; bk0 = cbase + c; }
            if (d1 < best1) { best1 = d1; bk1 = cbase + c; }
        }
    }

    pd[w * 128 + tpx * 2]     = best0;
    pd[w * 128 + tpx * 2 + 1] = best1;
    pk[w * 128 + tpx * 2]     = bk0;
    pk[w * 128 + tpx * 2 + 1] = bk1;
    __syncthreads();

    if (tid < 128) {
        float bd = pd[tid]; int bk = pk[tid];
#pragma unroll
        for (int ww = 1; ww < 4; ww++) {
            const float od = pd[ww * 128 + tid];
            if (od < bd) { bd = od; bk = pk[ww * 128 + tid]; }
        }
        bidx_sh[tid] = bk;
    }
    __syncthreads();

    {
        const int p  = tid & 127;
        const int d0 = (tid >> 7) * 32;
        const int bk = bidx_sh[p];
        const float4* __restrict__ cp4 = (const float4*)(cb + (size_t)bk * 64 + d0);
        float* __restrict__ qb = q + ((size_t)b * 64 + d0) * 4096 + hw0 + p;
#pragma unroll
        for (int i = 0; i < 8; i++) {
            const float4 v = cp4[i];
            qb[(size_t)(4 * i + 0) * 4096] = v.x;
            qb[(size_t)(4 * i + 1) * 4096] = v.y;
            qb[(size_t)(4 * i + 2) * 4096] = v.z;
            qb[(size_t)(4 * i + 3) * 4096] = v.w;
        }
    }
}

extern "C" void kernel_launch(void* const* d_in, const int* in_sizes, int n_in,
                              void* d_out, int out_size, void* d_ws, size_t ws_size,
                              hipStream_t stream) {
    const float* x      = (const float*)d_in[0];
    const float* w_e1   = (const float*)d_in[1];
    const float* b_e1   = (const float*)d_in[2];
    const float* w_e2   = (const float*)d_in[3];
    const float* b_e2   = (const float*)d_in[4];
    const float* w_er1a = (const float*)d_in[5];
    const float* w_er1b = (const float*)d_in[6];
    const float* w_er2a = (const float*)d_in[7];
    const float* w_er2b = (const float*)d_in[8];
    const float* w_pre  = (const float*)d_in[9];
    const float* b_pre  = (const float*)d_in[10];
    const float* cbk    = (const float*)d_in[11];
    const float* w_d1   = (const float*)d_in[12];
    const float* b_d1   = (const float*)d_in[13];
    const float* w_dr1a = (const float*)d_in[14];
    const float* w_dr1b = (const float*)d_in[15];
    const float* w_dr2a = (const float*)d_in[16];
    const float* w_dr2b = (const float*)d_in[17];
    const float* w_t1   = (const float*)d_in[18];
    const float* b_t1   = (const float*)d_in[19];
    const float* w_t2   = (const float*)d_in[20];
    const float* b_t2   = (const float*)d_in[21];
    float* out = (float*)d_out;

    float* A  = (float*)d_ws;            // 16777216 floats (scratch + t1 out)
    float* Bb = A  + 16777216;           // (32,64,64,64) = 8388608
    float* C  = Bb + 8388608;            // 4194304 (unused after fusion)
    float* D  = C  + 4194304;            // (32,64,64,64) = 8388608
    float* WR = D  + 8388608;            // repacked weights + cbT (221696)
    float* EE = WR + 221696;             // ee (512)

    float* r_e1  = WR;
    float* r_e2  = WR + 512;
    float* r_er1a = WR + 33280;
    float* r_er1b = WR + 51712;
    float* r_er2a = WR + 53760;
    float* r_er2b = WR + 72192;
    float* r_pre = WR + 74240;
    float* r_d1  = WR + 78336;
    float* r_dr1a = WR + 115200;
    float* r_dr1b = WR + 133632;
    float* r_dr2a = WR + 135680;
    float* r_dr2b = WR + 154112;
    float* r_t1  = WR + 156160;
    float* r_cbT = WR + 188928;

    const dim3 blk(256);
    const dim3 blk512(512);

    repack_all<<<dim3(866), blk, 0, stream>>>(
        w_e1, w_e2, w_er1a, w_er1b, w_er2a, w_er2b, w_pre, w_d1,
        w_dr1a, w_dr1b, w_dr2a, w_dr2b, w_t1, cbk, WR);
    vq_prep_ee<<<dim3(2), blk, 0, stream>>>(cbk, EE);

    // Encoder
    conv_gemm<32, 32, 1, 4, 2, 1, false, true, false, true>
        <<<dim3(2048, 1), blk, 0, stream>>>(x, r_e1, b_e1, nullptr, A,
                                            256, 256, 128, 128);
    conv4s2_tile<<<dim3(1024), blk512, 0, stream>>>(A, r_e2, b_e2, Bb);
    // er1: Bb -> A ; er2: A -> Bb (ping-pong avoids in-place halo race)
    res_tile<<<dim3(512), blk512, 0, stream>>>(Bb, r_er1a, r_er1b, A);
    res_tile<<<dim3(512), blk512, 0, stream>>>(A, r_er2a, r_er2b, Bb);
    // pre: stage-once 1x1
    conv1x1_tile<<<dim3(512), blk512, 0, stream>>>(Bb, r_pre, b_pre, D);
    // VQ
    vq_gemm<<<dim3(1024), blk, 0, stream>>>(D, cbk, r_cbT, EE, Bb);
    // Decoder
    conv3_tile<<<dim3(512), blk512, 0, stream>>>(Bb, r_d1, b_d1, D);
    // dr1: D -> A ; dr2: A -> D
    res_tile<<<dim3(512), blk512, 0, stream>>>(D, r_dr1a, r_dr1b, A);
    res_tile<<<dim3(512), blk512, 0, stream>>>(A, r_dr2a, r_dr2b, D);
    // t1 stage-once: grid 512, both pr per block
    convt_tile<<<dim3(512), blk512, 0, stream>>>(D, r_t1, b_t1, A);
    // t2
    convt2_quad<<<dim3(64, 32), blk, 0, stream>>>(A, w_t2, b_t2, out, 32);
}